// Round 5
// baseline (111.357 us; speedup 1.0000x reference)
//
#include <hip/hip_runtime.h>

typedef __attribute__((ext_vector_type(8))) short short8;   // 8 bf16 (4 VGPRs)
typedef __attribute__((ext_vector_type(4))) float f32x4;    // 4 fp32
typedef __attribute__((ext_vector_type(2))) unsigned int u32x2;

#define CTX 32
#define ND  64
#define NH  64
#define LOG2E_8 11.541560327111707f   // 8 * log2(e), folded into M
#define NB_PER_WAVE 2

// ---- LDS layout (bytes) ----
// Shared Mt tiles, 128 B rows, XOR-swizzled (16B block ^ (row&7))
#define OFF_MH 0                 // MtH [64][64] bf16
#define OFF_ML 8192              // MtL
#define OFF_WAVE 16384
// per-wave region (6144 B):
//   rtH [32][40] @0 (2560), rtL @2560 (2560)   -- tmp round-trip, stride 80 B
//                                                 (dead before softmax)
//   vT  [64][32] @0 stride 64 (4096)           -- aliases rt (written after rt dead)
//   P   [32][32] @4096 stride 64 (2048)        -- aliases rt tail (written after rt dead,
//                                                 disjoint from vT)
#define PWSTR 80
#define PW_RTH 0
#define PW_RTL 2560
#define PW_VT  0
#define PW_P   4096
#define WAVE_BYTES 6144
#define LDS_BYTES (OFF_WAVE + 4 * WAVE_BYTES)   // 40960 -> 4 WG/CU (16 waves) exact

__device__ __forceinline__ unsigned short f2bf(float f) {
  unsigned int u = __builtin_bit_cast(unsigned int, f);
  u += 0x7FFFu + ((u >> 16) & 1u);     // RNE
  return (unsigned short)(u >> 16);
}
__device__ __forceinline__ float bf2f(unsigned short b) {
  unsigned int u = ((unsigned int)b) << 16;
  return __builtin_bit_cast(float, u);
}
__device__ __forceinline__ unsigned int pk2(float a, float b) {
  return (unsigned int)f2bf(a) | ((unsigned int)f2bf(b) << 16);
}

#define MFMA(a, b, c) __builtin_amdgcn_mfma_f32_16x16x32_bf16((a), (b), (c), 0, 0, 0)

// ---- precompute Mt = (Wq Wk^T)^T * 8*log2(e) (bf16 hi/lo) and WvT (bf16), into ws ----
__global__ __launch_bounds__(256) void mk_m(
    const float* __restrict__ Wq, const float* __restrict__ Wk,
    const float* __restrict__ Wv,
    unsigned short* __restrict__ MtH, unsigned short* __restrict__ MtL,
    unsigned short* __restrict__ WvT)
{
  const int idx = blockIdx.x * 256 + threadIdx.x;   // [0,4096): idx = dp*64 + d
  const int dp = idx >> 6, d = idx & 63;
  const float* wq = Wq + d * 64;
  const float* wk = Wk + dp * 64;
  float acc = 0.f;
  #pragma unroll
  for (int h = 0; h < 64; ++h) acc = fmaf(wq[h], wk[h], acc);
  acc *= LOG2E_8;
  const unsigned short hi = f2bf(acc);
  MtH[idx] = hi;
  MtL[idx] = f2bf(acc - bf2f(hi));
  WvT[idx] = f2bf(Wv[d * 64 + dp]);   // WvT[h=dp][d]
}

__device__ __forceinline__ void load_x(const float* __restrict__ xb,
                                       f32x4 (&xr)[2][2][2], int c, int g) {
  #pragma unroll
  for (int mt = 0; mt < 2; ++mt)
    #pragma unroll
    for (int kt = 0; kt < 2; ++kt) {
      const float* p = xb + (16 * mt + c) * ND + 32 * kt + 8 * g;
      xr[mt][kt][0] = *(const f32x4*)(p);
      xr[mt][kt][1] = *(const f32x4*)(p + 4);
    }
}

__device__ __forceinline__ void compute_batch(
    const f32x4 (&xr)[2][2][2], const short8 (&bvr)[4][2], char* lds, char* wl,
    float* __restrict__ ob, int c, int g)
{
  // ---- split x -> A-frags hi/lo. A[lane&15][8*(lane>>4)+j] ----
  short8 xh[2][2], xl[2][2];
  #pragma unroll
  for (int mt = 0; mt < 2; ++mt) {
    #pragma unroll
    for (int kt = 0; kt < 2; ++kt) {
      short8 hi, lo;
      #pragma unroll
      for (int half = 0; half < 2; ++half) {
        #pragma unroll
        for (int j = 0; j < 4; ++j) {
          const float f = xr[mt][kt][half][j];
          const unsigned short h = f2bf(f);
          hi[4 * half + j] = (short)h;
          lo[4 * half + j] = (short)f2bf(f - bf2f(h));
        }
      }
      xh[mt][kt] = hi;
      xl[mt][kt] = lo;
    }
  }

  // ---- tmp = X·Mt (3-term) per 32-col half, then P^T += X·tmp^T ----
  f32x4 pa[2][2] = {{{0.f,0.f,0.f,0.f},{0.f,0.f,0.f,0.f}},
                    {{0.f,0.f,0.f,0.f},{0.f,0.f,0.f,0.f}}};
  #pragma unroll
  for (int kt = 0; kt < 2; ++kt) {
    #pragma unroll
    for (int ntl = 0; ntl < 2; ++ntl) {
      const int nt = 2 * kt + ntl;
      f32x4 a0 = {0.f, 0.f, 0.f, 0.f};
      f32x4 a1 = {0.f, 0.f, 0.f, 0.f};
      #pragma unroll
      for (int kk = 0; kk < 2; ++kk) {
        const int row = 16 * nt + c;
        const int byte = row * 128 + ((64 * kk + 16 * g) ^ ((row & 7) << 4));
        const short8 bh = *(const short8*)(lds + OFF_MH + byte);
        const short8 bl = *(const short8*)(lds + OFF_ML + byte);
        a0 = MFMA(xh[0][kk], bh, a0);
        a0 = MFMA(xh[0][kk], bl, a0);
        a0 = MFMA(xl[0][kk], bh, a0);
        a1 = MFMA(xh[1][kk], bh, a1);
        a1 = MFMA(xh[1][kk], bl, a1);
        a1 = MFMA(xl[1][kk], bh, a1);
      }
      // D-frag: tmp[row=4g+j (+16)][col=16nt+c]. Store hi/lo (col within 32-half).
      #pragma unroll
      for (int j = 0; j < 4; ++j) {
        const int col2 = 2 * (16 * ntl + c);
        const int off0 = (4 * g + j) * PWSTR + col2;
        const int off1 = (16 + 4 * g + j) * PWSTR + col2;
        const unsigned short h0 = f2bf(a0[j]);
        *(unsigned short*)(wl + PW_RTH + off0) = h0;
        *(unsigned short*)(wl + PW_RTL + off0) = f2bf(a0[j] - bf2f(h0));
        const unsigned short h1 = f2bf(a1[j]);
        *(unsigned short*)(wl + PW_RTH + off1) = h1;
        *(unsigned short*)(wl + PW_RTL + off1) = f2bf(a1[j] - bf2f(h1));
      }
    }
    // read tmp back (same wave wrote -> in-order DS, no barrier)
    short8 tH[2], tL[2];
    #pragma unroll
    for (int i = 0; i < 2; ++i) {
      const int off = (16 * i + c) * PWSTR + 16 * g;
      tH[i] = *(const short8*)(wl + PW_RTH + off);
      tL[i] = *(const short8*)(wl + PW_RTL + off);
    }
    // P^T = X·tmp^T: A = x frag (k = d' chunk kt), B = tmp read (B[k][n]=tmp[n][k])
    #pragma unroll
    for (int mt = 0; mt < 2; ++mt) {
      #pragma unroll
      for (int nt2 = 0; nt2 < 2; ++nt2) {
        pa[mt][nt2] = MFMA(xh[mt][kt], tH[nt2], pa[mt][nt2]);
        pa[mt][nt2] = MFMA(xl[mt][kt], tH[nt2], pa[mt][nt2]);
        pa[mt][nt2] = MFMA(xh[mt][kt], tL[nt2], pa[mt][nt2]);
      }
    }
  }

  // ---- softmax on P^T frags: pa[mt][nt][j] = P[t=16nt+c][s=16mt+4g+j] ----
  char* const pbuf = wl + PW_P;
  #pragma unroll
  for (int nt = 0; nt < 2; ++nt) {
    const int t = 16 * nt + c;
    float v[8];
    #pragma unroll
    for (int mt = 0; mt < 2; ++mt)
      #pragma unroll
      for (int j = 0; j < 4; ++j) {
        const int s = 16 * mt + 4 * g + j;
        v[4 * mt + j] = (s <= t) ? pa[mt][nt][j] : -__builtin_inff();
      }
    float m = fmaxf(fmaxf(fmaxf(v[0], v[1]), fmaxf(v[2], v[3])),
                    fmaxf(fmaxf(v[4], v[5]), fmaxf(v[6], v[7])));
    m = fmaxf(m, __shfl_xor(m, 16));
    m = fmaxf(m, __shfl_xor(m, 32));
    float e[8], ssum = 0.f;
    #pragma unroll
    for (int i = 0; i < 8; ++i) { e[i] = exp2f(v[i] - m); ssum += e[i]; }
    ssum += __shfl_xor(ssum, 16);
    ssum += __shfl_xor(ssum, 32);
    const float r = __builtin_amdgcn_rcpf(ssum);
    #pragma unroll
    for (int mt = 0; mt < 2; ++mt) {
      const u32x2 w2 = {pk2(e[4 * mt] * r, e[4 * mt + 1] * r),
                        pk2(e[4 * mt + 2] * r, e[4 * mt + 3] * r)};
      *(u32x2*)(pbuf + t * 64 + 32 * mt + 8 * g) = w2;   // P[t][16mt+4g..+3]
    }
  }

  // ---- v = X·Wv (single term, weights in regs), stored transposed vT[h][s] ----
  #pragma unroll
  for (int nt = 0; nt < 4; ++nt) {
    f32x4 a0 = {0.f, 0.f, 0.f, 0.f};
    f32x4 a1 = {0.f, 0.f, 0.f, 0.f};
    #pragma unroll
    for (int kk = 0; kk < 2; ++kk) {
      a0 = MFMA(xh[0][kk], bvr[nt][kk], a0);
      a1 = MFMA(xh[1][kk], bvr[nt][kk], a1);
    }
    // a0[j] = V[s=4g+j][h=16nt+c]; a1[j] = V[16+4g+j][h]. Pack along s, stride 64.
    char* const vrow = wl + PW_VT + (16 * nt + c) * 64;
    const u32x2 w0 = {pk2(a0[0], a0[1]), pk2(a0[2], a0[3])};
    const u32x2 w1 = {pk2(a1[0], a1[1]), pk2(a1[2], a1[3])};
    *(u32x2*)(vrow + 8 * g)      = w0;
    *(u32x2*)(vrow + 32 + 8 * g) = w1;
  }

  // ---- O^T = V^T·P^T (K = 32): A = vT A-frag, B = P A-layout read ----
  const short8 ap0 = *(const short8*)(pbuf + c * 64 + 16 * g);          // t = c
  const short8 ap1 = *(const short8*)(pbuf + (16 + c) * 64 + 16 * g);   // t = 16+c
  #pragma unroll
  for (int mh = 0; mh < 4; ++mh) {
    const short8 bv = *(const short8*)(wl + PW_VT + (16 * mh + c) * 64 + 16 * g);
    f32x4 o0 = {0.f, 0.f, 0.f, 0.f};
    f32x4 o1 = {0.f, 0.f, 0.f, 0.f};
    o0 = MFMA(bv, ap0, o0);   // D[m=h][n=t] = O^T
    o1 = MFMA(bv, ap1, o1);
    // o0[j] = O[t=c][h=16mh+4g+j] -> contiguous dwordx4
    *(f32x4*)(ob + c * NH + 16 * mh + 4 * g)        = o0;
    *(f32x4*)(ob + (16 + c) * NH + 16 * mh + 4 * g) = o1;
  }
}

__global__ __launch_bounds__(256, 4) void head_fused(
    const float* __restrict__ x,
    const unsigned short* __restrict__ MtH, const unsigned short* __restrict__ MtL,
    const unsigned short* __restrict__ WvT,
    float* __restrict__ out, int wstride)
{
  __shared__ __align__(16) char lds[LDS_BYTES];
  const int tid = threadIdx.x;

  // ---- stage Mt hi/lo (u32 swizzled copies from ws) ----
  {
    const unsigned int* srcH = (const unsigned int*)MtH;
    const unsigned int* srcL = (const unsigned int*)MtL;
    #pragma unroll
    for (int i = 0; i < 8; ++i) {
      const int e = tid + 256 * i;            // u32 index [0,2048)
      const int row = e >> 5;
      const int byte = row * 128 + (((e & 31) * 4) ^ ((row & 7) << 4));
      *(unsigned int*)(lds + OFF_MH + byte) = srcH[e];
      *(unsigned int*)(lds + OFF_ML + byte) = srcL[e];
    }
  }
  __syncthreads();

  const int wid  = tid >> 6;
  const int lane = tid & 63;
  const int c = lane & 15;
  const int g = lane >> 4;
  char* const wl = lds + OFF_WAVE + wid * WAVE_BYTES;

  // ---- WvT B-frags -> registers once per wave (wave-invariant, 32 VGPR) ----
  short8 bvr[4][2];
  #pragma unroll
  for (int nt = 0; nt < 4; ++nt)
    #pragma unroll
    for (int kk = 0; kk < 2; ++kk)
      bvr[nt][kk] = *(const short8*)(WvT + (16 * nt + c) * 64 + 32 * kk + 8 * g);

  const int w = blockIdx.x * 4 + wid;         // [0, wstride)

  f32x4 xc[2][2][2];
  load_x(x + (long)w * (CTX * ND), xc, c, g);

  #pragma unroll
  for (int it = 0; it < NB_PER_WAVE; ++it) {
    const long b = (long)w + (long)it * wstride;
    f32x4 xn[2][2][2];
    if (it + 1 < NB_PER_WAVE)
      load_x(x + (b + wstride) * (CTX * ND), xn, c, g);   // prefetch, overlaps compute
    compute_batch(xc, bvr, lds, wl, out + b * (CTX * NH), c, g);
    if (it + 1 < NB_PER_WAVE) {
      #pragma unroll
      for (int i = 0; i < 2; ++i)
        #pragma unroll
        for (int k = 0; k < 2; ++k)
          #pragma unroll
          for (int h = 0; h < 2; ++h) xc[i][k][h] = xn[i][k][h];
    }
  }
}

extern "C" void kernel_launch(void* const* d_in, const int* in_sizes, int n_in,
                              void* d_out, int out_size, void* d_ws, size_t ws_size,
                              hipStream_t stream) {
  // setup_inputs order: x, Wk, Wq, Wv  (all fp32)
  const float* x  = (const float*)d_in[0];
  const float* Wk = (const float*)d_in[1];
  const float* Wq = (const float*)d_in[2];
  const float* Wv = (const float*)d_in[3];
  float* out = (float*)d_out;

  unsigned short* MtH = (unsigned short*)d_ws;          // [64][64] bf16
  unsigned short* MtL = MtH + 64 * 64;
  unsigned short* WvT = MtL + 64 * 64;

  mk_m<<<dim3(16), dim3(256), 0, stream>>>(Wq, Wk, Wv, MtH, MtL, WvT);

  const int batch = in_sizes[0] / (CTX * ND);           // 16384
  const int wstride = batch / NB_PER_WAVE;              // 8192 waves
  head_fused<<<dim3(wstride / 4), dim3(256), 0, stream>>>(x, MtH, MtL, WvT, out, wstride);
}

// Round 6
// 72.687 us; speedup vs baseline: 1.5320x; 1.5320x over previous
//
#include <hip/hip_runtime.h>

typedef __attribute__((ext_vector_type(8))) short short8;   // 8 bf16 (4 VGPRs)
typedef __attribute__((ext_vector_type(4))) float f32x4;    // 4 fp32
typedef __attribute__((ext_vector_type(2))) unsigned int u32x2;

#define CTX 32
#define ND  64
#define NH  64
#define LOG2E_8 11.541560327111707f   // 8 * log2(e), folded into M
#define NB_PER_WAVE 2

// ---- LDS layout (bytes) ----
// Shared Mt tiles, 128 B rows, XOR-swizzled (16B block ^ (row&7))
#define OFF_MH 0                 // MtH [64][64] bf16
#define OFF_ML 8192              // MtL
#define OFF_WAVE 16384
// per-wave region (6144 B):
//   rtH [32][40] @0 (2560), rtL @2560 (2560)   -- tmp round-trip, stride 80 B
//                                                 (dead before softmax)
//   vT  [64][32] @0 stride 64 (4096)           -- aliases rt (written after rt dead)
//   P   [32][32] @4096 stride 64 (2048)        -- aliases rt tail (written after rt dead,
//                                                 disjoint from vT)
#define PWSTR 80
#define PW_RTH 0
#define PW_RTL 2560
#define PW_VT  0
#define PW_P   4096
#define WAVE_BYTES 6144
#define LDS_BYTES (OFF_WAVE + 4 * WAVE_BYTES)   // 40960 -> 4 WG/CU if VGPR <= 128

__device__ __forceinline__ unsigned short f2bf(float f) {
  unsigned int u = __builtin_bit_cast(unsigned int, f);
  u += 0x7FFFu + ((u >> 16) & 1u);     // RNE
  return (unsigned short)(u >> 16);
}
__device__ __forceinline__ float bf2f(unsigned short b) {
  unsigned int u = ((unsigned int)b) << 16;
  return __builtin_bit_cast(float, u);
}
__device__ __forceinline__ unsigned int pk2(float a, float b) {
  return (unsigned int)f2bf(a) | ((unsigned int)f2bf(b) << 16);
}

#define MFMA(a, b, c) __builtin_amdgcn_mfma_f32_16x16x32_bf16((a), (b), (c), 0, 0, 0)

// ---- precompute Mt = (Wq Wk^T)^T * 8*log2(e) (bf16 hi/lo) and WvT (bf16), into ws ----
__global__ __launch_bounds__(256) void mk_m(
    const float* __restrict__ Wq, const float* __restrict__ Wk,
    const float* __restrict__ Wv,
    unsigned short* __restrict__ MtH, unsigned short* __restrict__ MtL,
    unsigned short* __restrict__ WvT)
{
  const int idx = blockIdx.x * 256 + threadIdx.x;   // [0,4096): idx = dp*64 + d
  const int dp = idx >> 6, d = idx & 63;
  const float* wq = Wq + d * 64;
  const float* wk = Wk + dp * 64;
  float acc = 0.f;
  #pragma unroll
  for (int h = 0; h < 64; ++h) acc = fmaf(wq[h], wk[h], acc);
  acc *= LOG2E_8;
  const unsigned short hi = f2bf(acc);
  MtH[idx] = hi;
  MtL[idx] = f2bf(acc - bf2f(hi));
  WvT[idx] = f2bf(Wv[d * 64 + dp]);   // WvT[h=dp][d]
}

__device__ __forceinline__ void load_x(const float* __restrict__ xb,
                                       f32x4 (&xr)[2][2][2], int c, int g) {
  #pragma unroll
  for (int mt = 0; mt < 2; ++mt)
    #pragma unroll
    for (int kt = 0; kt < 2; ++kt) {
      const float* p = xb + (16 * mt + c) * ND + 32 * kt + 8 * g;
      xr[mt][kt][0] = *(const f32x4*)(p);
      xr[mt][kt][1] = *(const f32x4*)(p + 4);
    }
}

__device__ __forceinline__ void compute_batch(
    const f32x4 (&xr)[2][2][2], const short8 (&bvr)[4][2], char* lds, char* wl,
    float* __restrict__ ob, int c, int g)
{
  // ---- split x -> A-frags hi/lo. A[lane&15][8*(lane>>4)+j] ----
  short8 xh[2][2], xl[2][2];
  #pragma unroll
  for (int mt = 0; mt < 2; ++mt) {
    #pragma unroll
    for (int kt = 0; kt < 2; ++kt) {
      short8 hi, lo;
      #pragma unroll
      for (int half = 0; half < 2; ++half) {
        #pragma unroll
        for (int j = 0; j < 4; ++j) {
          const float f = xr[mt][kt][half][j];
          const unsigned short h = f2bf(f);
          hi[4 * half + j] = (short)h;
          lo[4 * half + j] = (short)f2bf(f - bf2f(h));
        }
      }
      xh[mt][kt] = hi;
      xl[mt][kt] = lo;
    }
  }

  // ---- tmp = X·Mt (3-term) per 32-col half, then P^T += X·tmp^T ----
  f32x4 pa[2][2] = {{{0.f,0.f,0.f,0.f},{0.f,0.f,0.f,0.f}},
                    {{0.f,0.f,0.f,0.f},{0.f,0.f,0.f,0.f}}};
  #pragma unroll
  for (int kt = 0; kt < 2; ++kt) {
    #pragma unroll
    for (int ntl = 0; ntl < 2; ++ntl) {
      const int nt = 2 * kt + ntl;
      f32x4 a0 = {0.f, 0.f, 0.f, 0.f};
      f32x4 a1 = {0.f, 0.f, 0.f, 0.f};
      #pragma unroll
      for (int kk = 0; kk < 2; ++kk) {
        const int row = 16 * nt + c;
        const int byte = row * 128 + ((64 * kk + 16 * g) ^ ((row & 7) << 4));
        const short8 bh = *(const short8*)(lds + OFF_MH + byte);
        const short8 bl = *(const short8*)(lds + OFF_ML + byte);
        a0 = MFMA(xh[0][kk], bh, a0);
        a0 = MFMA(xh[0][kk], bl, a0);
        a0 = MFMA(xl[0][kk], bh, a0);
        a1 = MFMA(xh[1][kk], bh, a1);
        a1 = MFMA(xh[1][kk], bl, a1);
        a1 = MFMA(xl[1][kk], bh, a1);
      }
      // D-frag: tmp[row=4g+j (+16)][col=16nt+c]. Store hi/lo (col within 32-half).
      #pragma unroll
      for (int j = 0; j < 4; ++j) {
        const int col2 = 2 * (16 * ntl + c);
        const int off0 = (4 * g + j) * PWSTR + col2;
        const int off1 = (16 + 4 * g + j) * PWSTR + col2;
        const unsigned short h0 = f2bf(a0[j]);
        *(unsigned short*)(wl + PW_RTH + off0) = h0;
        *(unsigned short*)(wl + PW_RTL + off0) = f2bf(a0[j] - bf2f(h0));
        const unsigned short h1 = f2bf(a1[j]);
        *(unsigned short*)(wl + PW_RTH + off1) = h1;
        *(unsigned short*)(wl + PW_RTL + off1) = f2bf(a1[j] - bf2f(h1));
      }
    }
    // read tmp back (same wave wrote -> in-order DS, no barrier)
    short8 tH[2], tL[2];
    #pragma unroll
    for (int i = 0; i < 2; ++i) {
      const int off = (16 * i + c) * PWSTR + 16 * g;
      tH[i] = *(const short8*)(wl + PW_RTH + off);
      tL[i] = *(const short8*)(wl + PW_RTL + off);
    }
    // P^T = X·tmp^T: A = x frag (k = d' chunk kt), B = tmp read (B[k][n]=tmp[n][k])
    #pragma unroll
    for (int mt = 0; mt < 2; ++mt) {
      #pragma unroll
      for (int nt2 = 0; nt2 < 2; ++nt2) {
        pa[mt][nt2] = MFMA(xh[mt][kt], tH[nt2], pa[mt][nt2]);
        pa[mt][nt2] = MFMA(xl[mt][kt], tH[nt2], pa[mt][nt2]);
        pa[mt][nt2] = MFMA(xh[mt][kt], tL[nt2], pa[mt][nt2]);
      }
    }
  }

  // ---- softmax on P^T frags: pa[mt][nt][j] = P[t=16nt+c][s=16mt+4g+j] ----
  char* const pbuf = wl + PW_P;
  #pragma unroll
  for (int nt = 0; nt < 2; ++nt) {
    const int t = 16 * nt + c;
    float v[8];
    #pragma unroll
    for (int mt = 0; mt < 2; ++mt)
      #pragma unroll
      for (int j = 0; j < 4; ++j) {
        const int s = 16 * mt + 4 * g + j;
        v[4 * mt + j] = (s <= t) ? pa[mt][nt][j] : -__builtin_inff();
      }
    float m = fmaxf(fmaxf(fmaxf(v[0], v[1]), fmaxf(v[2], v[3])),
                    fmaxf(fmaxf(v[4], v[5]), fmaxf(v[6], v[7])));
    m = fmaxf(m, __shfl_xor(m, 16));
    m = fmaxf(m, __shfl_xor(m, 32));
    float e[8], ssum = 0.f;
    #pragma unroll
    for (int i = 0; i < 8; ++i) { e[i] = exp2f(v[i] - m); ssum += e[i]; }
    ssum += __shfl_xor(ssum, 16);
    ssum += __shfl_xor(ssum, 32);
    const float r = __builtin_amdgcn_rcpf(ssum);
    #pragma unroll
    for (int mt = 0; mt < 2; ++mt) {
      const u32x2 w2 = {pk2(e[4 * mt] * r, e[4 * mt + 1] * r),
                        pk2(e[4 * mt + 2] * r, e[4 * mt + 3] * r)};
      *(u32x2*)(pbuf + t * 64 + 32 * mt + 8 * g) = w2;   // P[t][16mt+4g..+3]
    }
  }

  // ---- v = X·Wv (single term, weights in regs), stored transposed vT[h][s] ----
  #pragma unroll
  for (int nt = 0; nt < 4; ++nt) {
    f32x4 a0 = {0.f, 0.f, 0.f, 0.f};
    f32x4 a1 = {0.f, 0.f, 0.f, 0.f};
    #pragma unroll
    for (int kk = 0; kk < 2; ++kk) {
      a0 = MFMA(xh[0][kk], bvr[nt][kk], a0);
      a1 = MFMA(xh[1][kk], bvr[nt][kk], a1);
    }
    // a0[j] = V[s=4g+j][h=16nt+c]; a1[j] = V[16+4g+j][h]. Pack along s, stride 64.
    char* const vrow = wl + PW_VT + (16 * nt + c) * 64;
    const u32x2 w0 = {pk2(a0[0], a0[1]), pk2(a0[2], a0[3])};
    const u32x2 w1 = {pk2(a1[0], a1[1]), pk2(a1[2], a1[3])};
    *(u32x2*)(vrow + 8 * g)      = w0;
    *(u32x2*)(vrow + 32 + 8 * g) = w1;
  }

  // ---- O^T = V^T·P^T (K = 32): A = vT A-frag, B = P A-layout read ----
  const short8 ap0 = *(const short8*)(pbuf + c * 64 + 16 * g);          // t = c
  const short8 ap1 = *(const short8*)(pbuf + (16 + c) * 64 + 16 * g);   // t = 16+c
  #pragma unroll
  for (int mh = 0; mh < 4; ++mh) {
    const short8 bv = *(const short8*)(wl + PW_VT + (16 * mh + c) * 64 + 16 * g);
    f32x4 o0 = {0.f, 0.f, 0.f, 0.f};
    f32x4 o1 = {0.f, 0.f, 0.f, 0.f};
    o0 = MFMA(bv, ap0, o0);   // D[m=h][n=t] = O^T
    o1 = MFMA(bv, ap1, o1);
    // o0[j] = O[t=c][h=16mh+4g+j] -> contiguous dwordx4
    *(f32x4*)(ob + c * NH + 16 * mh + 4 * g)        = o0;
    *(f32x4*)(ob + (16 + c) * NH + 16 * mh + 4 * g) = o1;
  }
}

__global__ __launch_bounds__(256, 3) void head_fused(
    const float* __restrict__ x,
    const unsigned short* __restrict__ MtH, const unsigned short* __restrict__ MtL,
    const unsigned short* __restrict__ WvT,
    float* __restrict__ out, int wstride)
{
  __shared__ __align__(16) char lds[LDS_BYTES];
  const int tid = threadIdx.x;

  // ---- stage Mt hi/lo (u32 swizzled copies from ws) ----
  {
    const unsigned int* srcH = (const unsigned int*)MtH;
    const unsigned int* srcL = (const unsigned int*)MtL;
    #pragma unroll
    for (int i = 0; i < 8; ++i) {
      const int e = tid + 256 * i;            // u32 index [0,2048)
      const int row = e >> 5;
      const int byte = row * 128 + (((e & 31) * 4) ^ ((row & 7) << 4));
      *(unsigned int*)(lds + OFF_MH + byte) = srcH[e];
      *(unsigned int*)(lds + OFF_ML + byte) = srcL[e];
    }
  }
  __syncthreads();

  const int wid  = tid >> 6;
  const int lane = tid & 63;
  const int c = lane & 15;
  const int g = lane >> 4;
  char* const wl = lds + OFF_WAVE + wid * WAVE_BYTES;

  // ---- WvT B-frags -> registers once per wave (wave-invariant, 32 VGPR) ----
  short8 bvr[4][2];
  #pragma unroll
  for (int nt = 0; nt < 4; ++nt)
    #pragma unroll
    for (int kk = 0; kk < 2; ++kk)
      bvr[nt][kk] = *(const short8*)(WvT + (16 * nt + c) * 64 + 32 * kk + 8 * g);

  const int w = blockIdx.x * 4 + wid;         // [0, wstride)

  f32x4 xc[2][2][2];
  load_x(x + (long)w * (CTX * ND), xc, c, g);

  #pragma unroll
  for (int it = 0; it < NB_PER_WAVE; ++it) {
    const long b = (long)w + (long)it * wstride;
    f32x4 xn[2][2][2];
    if (it + 1 < NB_PER_WAVE)
      load_x(x + (b + wstride) * (CTX * ND), xn, c, g);   // prefetch, overlaps compute
    compute_batch(xc, bvr, lds, wl, out + b * (CTX * NH), c, g);
    if (it + 1 < NB_PER_WAVE) {
      #pragma unroll
      for (int i = 0; i < 2; ++i)
        #pragma unroll
        for (int k = 0; k < 2; ++k)
          #pragma unroll
          for (int h = 0; h < 2; ++h) xc[i][k][h] = xn[i][k][h];
    }
  }
}

extern "C" void kernel_launch(void* const* d_in, const int* in_sizes, int n_in,
                              void* d_out, int out_size, void* d_ws, size_t ws_size,
                              hipStream_t stream) {
  // setup_inputs order: x, Wk, Wq, Wv  (all fp32)
  const float* x  = (const float*)d_in[0];
  const float* Wk = (const float*)d_in[1];
  const float* Wq = (const float*)d_in[2];
  const float* Wv = (const float*)d_in[3];
  float* out = (float*)d_out;

  unsigned short* MtH = (unsigned short*)d_ws;          // [64][64] bf16
  unsigned short* MtL = MtH + 64 * 64;
  unsigned short* WvT = MtL + 64 * 64;

  mk_m<<<dim3(16), dim3(256), 0, stream>>>(Wq, Wk, Wv, MtH, MtL, WvT);

  const int batch = in_sizes[0] / (CTX * ND);           // 16384
  const int wstride = batch / NB_PER_WAVE;              // 8192 waves
  head_fused<<<dim3(wstride / 4), dim3(256), 0, stream>>>(x, MtH, MtL, WvT, out, wstride);
}

// Round 7
// 64.261 us; speedup vs baseline: 1.7329x; 1.1311x over previous
//
#include <hip/hip_runtime.h>

typedef __attribute__((ext_vector_type(8))) short short8;   // 8 bf16 (4 VGPRs)
typedef __attribute__((ext_vector_type(4))) float f32x4;    // 4 fp32
typedef __attribute__((ext_vector_type(2))) unsigned int u32x2;

#define CTX 32
#define ND  64
#define NH  64
#define LOG2E_8 11.541560327111707f   // 8 * log2(e), folded into M

// ---- LDS layout (bytes) ----
// Shared Mt tiles, 128 B rows, XOR-swizzled (16B block ^ (row&7))
#define OFF_MH 0                 // MtH [64][64] bf16
#define OFF_ML 8192              // MtL
#define OFF_WAVE 16384
// per-batch region (7168 B), 8 regions (4 waves x 2 batches):
//   rtH [32][40] @0 (2560), rtL @2560 (2560)   -- tmp round-trip, stride 80 B
//   vT  [64][40] @0 (5120)                     -- aliases rt (written after rt dead)
//   P   [32][32] @5120 (2048)                  -- stride 64 B
#define PWSTR 80
#define PW_RTH 0
#define PW_RTL 2560
#define PW_VT  0
#define PW_P   5120
#define WAVE_BYTES 7168
#define NREG 8
#define LDS_BYTES (OFF_WAVE + NREG * WAVE_BYTES)   // 73728 -> 2 WG/CU (16KB margin)

__device__ __forceinline__ unsigned short f2bf(float f) {
  unsigned int u = __builtin_bit_cast(unsigned int, f);
  u += 0x7FFFu + ((u >> 16) & 1u);     // RNE
  return (unsigned short)(u >> 16);
}
__device__ __forceinline__ float bf2f(unsigned short b) {
  unsigned int u = ((unsigned int)b) << 16;
  return __builtin_bit_cast(float, u);
}
__device__ __forceinline__ unsigned int pk2(float a, float b) {
  return (unsigned int)f2bf(a) | ((unsigned int)f2bf(b) << 16);
}

#define MFMA(a, b, c) __builtin_amdgcn_mfma_f32_16x16x32_bf16((a), (b), (c), 0, 0, 0)

// ---- precompute Mt = (Wq Wk^T)^T * 8*log2(e) (bf16 hi/lo) and WvT (bf16), into ws ----
__global__ __launch_bounds__(256) void mk_m(
    const float* __restrict__ Wq, const float* __restrict__ Wk,
    const float* __restrict__ Wv,
    unsigned short* __restrict__ MtH, unsigned short* __restrict__ MtL,
    unsigned short* __restrict__ WvT)
{
  const int idx = blockIdx.x * 256 + threadIdx.x;   // [0,4096): idx = dp*64 + d
  const int dp = idx >> 6, d = idx & 63;
  const float* wq = Wq + d * 64;
  const float* wk = Wk + dp * 64;
  float acc = 0.f;
  #pragma unroll
  for (int h = 0; h < 64; ++h) acc = fmaf(wq[h], wk[h], acc);
  acc *= LOG2E_8;
  const unsigned short hi = f2bf(acc);
  MtH[idx] = hi;
  MtL[idx] = f2bf(acc - bf2f(hi));
  WvT[idx] = f2bf(Wv[d * 64 + dp]);   // WvT[h=dp][d]
}

// ---- per-batch in-register state (two live per wave) ----
struct Batch {
  short8 xh[2][2], xl[2][2];
  f32x4  pa[2][2];
  char*  wl;        // this batch's LDS region
  float* ob;        // output base
};

__device__ __forceinline__ void load_x(const float* __restrict__ xb,
                                       f32x4 (&xr)[2][2][2], int c, int g) {
  #pragma unroll
  for (int mt = 0; mt < 2; ++mt)
    #pragma unroll
    for (int kt = 0; kt < 2; ++kt) {
      const float* p = xb + (16 * mt + c) * ND + 32 * kt + 8 * g;
      xr[mt][kt][0] = *(const f32x4*)(p);
      xr[mt][kt][1] = *(const f32x4*)(p + 4);
    }
}

__device__ __forceinline__ void split_x(Batch& s, const f32x4 (&xr)[2][2][2]) {
  #pragma unroll
  for (int mt = 0; mt < 2; ++mt)
    #pragma unroll
    for (int kt = 0; kt < 2; ++kt) {
      short8 hi, lo;
      #pragma unroll
      for (int half = 0; half < 2; ++half)
        #pragma unroll
        for (int j = 0; j < 4; ++j) {
          const float f = xr[mt][kt][half][j];
          const unsigned short h = f2bf(f);
          hi[4 * half + j] = (short)h;
          lo[4 * half + j] = (short)f2bf(f - bf2f(h));
        }
      s.xh[mt][kt] = hi;
      s.xl[mt][kt] = lo;
    }
  #pragma unroll
  for (int i = 0; i < 2; ++i)
    #pragma unroll
    for (int j = 0; j < 2; ++j) s.pa[i][j] = f32x4{0.f, 0.f, 0.f, 0.f};
}

// tmp = X·Mt (3-term) for one 16-col block nt = 2*kt+ntl; store hi/lo to rt
__device__ __forceinline__ void qk_fill(Batch& s, const char* lds,
                                        int kt, int ntl, int c, int g) {
  const int nt = 2 * kt + ntl;
  f32x4 a0 = {0.f, 0.f, 0.f, 0.f};
  f32x4 a1 = {0.f, 0.f, 0.f, 0.f};
  #pragma unroll
  for (int kk = 0; kk < 2; ++kk) {
    const int row = 16 * nt + c;
    const int byte = row * 128 + ((64 * kk + 16 * g) ^ ((row & 7) << 4));
    const short8 bh = *(const short8*)(lds + OFF_MH + byte);
    const short8 bl = *(const short8*)(lds + OFF_ML + byte);
    a0 = MFMA(s.xh[0][kk], bh, a0);
    a0 = MFMA(s.xh[0][kk], bl, a0);
    a0 = MFMA(s.xl[0][kk], bh, a0);
    a1 = MFMA(s.xh[1][kk], bh, a1);
    a1 = MFMA(s.xh[1][kk], bl, a1);
    a1 = MFMA(s.xl[1][kk], bh, a1);
  }
  // D-frag: tmp[row=4g+j (+16)][col=16nt+c]. Store hi/lo (col within 32-half).
  #pragma unroll
  for (int j = 0; j < 4; ++j) {
    const int col2 = 2 * (16 * ntl + c);
    const int off0 = (4 * g + j) * PWSTR + col2;
    const int off1 = (16 + 4 * g + j) * PWSTR + col2;
    const unsigned short h0 = f2bf(a0[j]);
    *(unsigned short*)(s.wl + PW_RTH + off0) = h0;
    *(unsigned short*)(s.wl + PW_RTL + off0) = f2bf(a0[j] - bf2f(h0));
    const unsigned short h1 = f2bf(a1[j]);
    *(unsigned short*)(s.wl + PW_RTH + off1) = h1;
    *(unsigned short*)(s.wl + PW_RTL + off1) = f2bf(a1[j] - bf2f(h1));
  }
}

// P^T += X·tmp^T over d' block kt (reads rt back as A-frags)
__device__ __forceinline__ void qk_consume(Batch& s, int kt, int c, int g) {
  short8 tH[2], tL[2];
  #pragma unroll
  for (int i = 0; i < 2; ++i) {
    const int off = (16 * i + c) * PWSTR + 16 * g;
    tH[i] = *(const short8*)(s.wl + PW_RTH + off);
    tL[i] = *(const short8*)(s.wl + PW_RTL + off);
  }
  #pragma unroll
  for (int mt = 0; mt < 2; ++mt)
    #pragma unroll
    for (int nt2 = 0; nt2 < 2; ++nt2) {
      s.pa[mt][nt2] = MFMA(s.xh[mt][kt], tH[nt2], s.pa[mt][nt2]);
      s.pa[mt][nt2] = MFMA(s.xl[mt][kt], tH[nt2], s.pa[mt][nt2]);
      s.pa[mt][nt2] = MFMA(s.xh[mt][kt], tL[nt2], s.pa[mt][nt2]);
    }
}

// causal mask + softmax; pa[mt][nt][j] = P[t=16nt+c][s=16mt+4g+j]; store P bf16
__device__ __forceinline__ void softmax_store(Batch& s, int c, int g) {
  char* const pbuf = s.wl + PW_P;
  #pragma unroll
  for (int nt = 0; nt < 2; ++nt) {
    const int t = 16 * nt + c;
    float v[8];
    #pragma unroll
    for (int mt = 0; mt < 2; ++mt)
      #pragma unroll
      for (int j = 0; j < 4; ++j) {
        const int sidx = 16 * mt + 4 * g + j;
        v[4 * mt + j] = (sidx <= t) ? s.pa[mt][nt][j] : -__builtin_inff();
      }
    float m = fmaxf(fmaxf(fmaxf(v[0], v[1]), fmaxf(v[2], v[3])),
                    fmaxf(fmaxf(v[4], v[5]), fmaxf(v[6], v[7])));
    m = fmaxf(m, __shfl_xor(m, 16));
    m = fmaxf(m, __shfl_xor(m, 32));
    float e[8], ssum = 0.f;
    #pragma unroll
    for (int i = 0; i < 8; ++i) { e[i] = exp2f(v[i] - m); ssum += e[i]; }
    ssum += __shfl_xor(ssum, 16);
    ssum += __shfl_xor(ssum, 32);
    const float r = __builtin_amdgcn_rcpf(ssum);
    #pragma unroll
    for (int mt = 0; mt < 2; ++mt) {
      const u32x2 w2 = {pk2(e[4 * mt] * r, e[4 * mt + 1] * r),
                        pk2(e[4 * mt + 2] * r, e[4 * mt + 3] * r)};
      *(u32x2*)(pbuf + t * 64 + 32 * mt + 8 * g) = w2;   // P[t][16mt+4g..+3]
    }
  }
}

// v = X·Wv (weights in regs), stored transposed vT[h][s] stride 80 (aliases rt)
__device__ __forceinline__ void vproj(Batch& s, const short8 (&bvr)[4][2],
                                      int c, int g) {
  #pragma unroll
  for (int nt = 0; nt < 4; ++nt) {
    f32x4 a0 = {0.f, 0.f, 0.f, 0.f};
    f32x4 a1 = {0.f, 0.f, 0.f, 0.f};
    #pragma unroll
    for (int kk = 0; kk < 2; ++kk) {
      a0 = MFMA(s.xh[0][kk], bvr[nt][kk], a0);
      a1 = MFMA(s.xh[1][kk], bvr[nt][kk], a1);
    }
    // a0[j] = V[s=4g+j][h=16nt+c]; a1[j] = V[16+4g+j][h]. Pack along s.
    char* const vrow = s.wl + PW_VT + (16 * nt + c) * PWSTR;
    const u32x2 w0 = {pk2(a0[0], a0[1]), pk2(a0[2], a0[3])};
    const u32x2 w1 = {pk2(a1[0], a1[1]), pk2(a1[2], a1[3])};
    *(u32x2*)(vrow + 8 * g)      = w0;
    *(u32x2*)(vrow + 32 + 8 * g) = w1;
  }
}

// O^T = V^T·P^T (K=32): A = vT A-frag, B = P A-layout read; store fp32 dwordx4
__device__ __forceinline__ void pv_store(Batch& s, int c, int g) {
  char* const pbuf = s.wl + PW_P;
  const short8 ap0 = *(const short8*)(pbuf + c * 64 + 16 * g);          // t = c
  const short8 ap1 = *(const short8*)(pbuf + (16 + c) * 64 + 16 * g);   // t = 16+c
  #pragma unroll
  for (int mh = 0; mh < 4; ++mh) {
    const short8 bv = *(const short8*)(s.wl + PW_VT + (16 * mh + c) * PWSTR + 16 * g);
    f32x4 o0 = {0.f, 0.f, 0.f, 0.f};
    f32x4 o1 = {0.f, 0.f, 0.f, 0.f};
    o0 = MFMA(bv, ap0, o0);   // D[m=h][n=t] = O^T
    o1 = MFMA(bv, ap1, o1);
    *(f32x4*)(s.ob + c * NH + 16 * mh + 4 * g)        = o0;
    *(f32x4*)(s.ob + (16 + c) * NH + 16 * mh + 4 * g) = o1;
  }
}

__global__ __launch_bounds__(256, 2) void head_fused(
    const float* __restrict__ x,
    const unsigned short* __restrict__ MtH, const unsigned short* __restrict__ MtL,
    const unsigned short* __restrict__ WvT,
    float* __restrict__ out)
{
  __shared__ __align__(16) char lds[LDS_BYTES];
  const int tid = threadIdx.x;

  // ---- stage Mt hi/lo (u32 swizzled copies from ws) ----
  {
    const unsigned int* srcH = (const unsigned int*)MtH;
    const unsigned int* srcL = (const unsigned int*)MtL;
    #pragma unroll
    for (int i = 0; i < 8; ++i) {
      const int e = tid + 256 * i;            // u32 index [0,2048)
      const int row = e >> 5;
      const int byte = row * 128 + (((e & 31) * 4) ^ ((row & 7) << 4));
      *(unsigned int*)(lds + OFF_MH + byte) = srcH[e];
      *(unsigned int*)(lds + OFF_ML + byte) = srcL[e];
    }
  }
  __syncthreads();

  const int wid  = tid >> 6;
  const int lane = tid & 63;
  const int c = lane & 15;
  const int g = lane >> 4;

  // ---- WvT B-frags -> registers once per wave (wave-invariant, 32 VGPR) ----
  short8 bvr[4][2];
  #pragma unroll
  for (int nt = 0; nt < 4; ++nt)
    #pragma unroll
    for (int kk = 0; kk < 2; ++kk)
      bvr[nt][kk] = *(const short8*)(WvT + (16 * nt + c) * 64 + 32 * kk + 8 * g);

  const int w = blockIdx.x * 4 + wid;        // wave id [0, 8192)
  const long bA = 2L * w, bB = 2L * w + 1;

  Batch A, B;
  A.wl = lds + OFF_WAVE + (wid * 2 + 0) * WAVE_BYTES;
  B.wl = lds + OFF_WAVE + (wid * 2 + 1) * WAVE_BYTES;
  A.ob = out + bA * (CTX * NH);
  B.ob = out + bB * (CTX * NH);

  f32x4 xrA[2][2][2], xrB[2][2][2];
  load_x(x + bA * (CTX * ND), xrA, c, g);
  load_x(x + bB * (CTX * ND), xrB, c, g);

  split_x(A, xrA);
  split_x(B, xrB);

  // ---- interleaved two-chain schedule ----
  #pragma unroll
  for (int kt = 0; kt < 2; ++kt) {
    qk_fill(A, lds, kt, 0, c, g);
    qk_fill(B, lds, kt, 0, c, g);
    qk_fill(A, lds, kt, 1, c, g);
    qk_fill(B, lds, kt, 1, c, g);
    qk_consume(A, kt, c, g);
    qk_consume(B, kt, c, g);
  }
  softmax_store(A, c, g);
  softmax_store(B, c, g);
  vproj(A, bvr, c, g);
  vproj(B, bvr, c, g);
  pv_store(A, c, g);
  pv_store(B, c, g);
}

extern "C" void kernel_launch(void* const* d_in, const int* in_sizes, int n_in,
                              void* d_out, int out_size, void* d_ws, size_t ws_size,
                              hipStream_t stream) {
  // setup_inputs order: x, Wk, Wq, Wv  (all fp32)
  const float* x  = (const float*)d_in[0];
  const float* Wk = (const float*)d_in[1];
  const float* Wq = (const float*)d_in[2];
  const float* Wv = (const float*)d_in[3];
  float* out = (float*)d_out;

  unsigned short* MtH = (unsigned short*)d_ws;          // [64][64] bf16
  unsigned short* MtL = MtH + 64 * 64;
  unsigned short* WvT = MtL + 64 * 64;

  mk_m<<<dim3(16), dim3(256), 0, stream>>>(Wq, Wk, Wv, MtH, MtL, WvT);

  const int batch = in_sizes[0] / (CTX * ND);           // 16384
  const int nwg = batch / 8;                            // 4 waves x 2 batches per WG
  head_fused<<<dim3(nwg), dim3(256), 0, stream>>>(x, MtH, MtL, WvT, out);
}

// Round 9
// 59.644 us; speedup vs baseline: 1.8670x; 1.0774x over previous
//
#include <hip/hip_runtime.h>
#include <hip/hip_bf16.h>

typedef __attribute__((ext_vector_type(8))) short short8;   // 8 bf16 (4 VGPRs)
typedef __attribute__((ext_vector_type(4))) float f32x4;    // 4 fp32
typedef __attribute__((ext_vector_type(2))) unsigned int u32x2;
typedef __attribute__((ext_vector_type(4))) unsigned int u32x4;

#define CTX 32
#define ND  64
#define NH  64
#define LOG2E_8 11.541560327111707f   // 8 * log2(e), folded into M
#define NB_PER_WAVE 2

// ---- LDS layout (bytes) ----
// Shared Mt tiles, 128 B rows, XOR-swizzled (16B block ^ (row&7))
#define OFF_MH 0                 // MtH [64][64] bf16
#define OFF_ML 8192              // MtL
#define OFF_WAVE 16384
// per-wave region (7680 B):
//   rtH [32][40] @0 (2560), rtL @2560 (2560)   -- tmp round-trip, stride 80 B
//   vT  [64][40] @0 (5120)                     -- aliases rt (written after rt dead)
//   P   [32][40] @5120 (2560)                  -- stride 80 B (2-way banks, was 64/8-way)
#define PWSTR 80
#define PW_RTH 0
#define PW_RTL 2560
#define PW_VT  0
#define PW_P   5120
#define WAVE_BYTES 7680
#define LDS_BYTES (OFF_WAVE + 4 * WAVE_BYTES)   // 47104 -> 3 WG/CU (141312 <= 160K)

__device__ __forceinline__ unsigned short f2bf(float f) {
  unsigned int u = __builtin_bit_cast(unsigned int, f);
  u += 0x7FFFu + ((u >> 16) & 1u);     // RNE (host-side precompute kernel only)
  return (unsigned short)(u >> 16);
}
__device__ __forceinline__ float bf2f(unsigned short b) {
  unsigned int u = ((unsigned int)b) << 16;
  return __builtin_bit_cast(float, u);
}
// packed RNE pair via native cast -> compiler emits HW cvt_pk path (m240)
__device__ __forceinline__ unsigned int pkrn(float a, float b) {
  const __hip_bfloat162 t = __float22bfloat162_rn(make_float2(a, b));
  unsigned int u;
  __builtin_memcpy(&u, &t, 4);
  return u;
}
__device__ __forceinline__ float2 unpk(unsigned int w) {
  __hip_bfloat162 t;
  __builtin_memcpy(&t, &w, 4);
  return __bfloat1622float2(t);
}

#define MFMA(a, b, c) __builtin_amdgcn_mfma_f32_16x16x32_bf16((a), (b), (c), 0, 0, 0)

// ---- precompute Mt = (Wq Wk^T)^T * 8*log2(e) (bf16 hi/lo) and WvT (bf16), into ws ----
__global__ __launch_bounds__(256) void mk_m(
    const float* __restrict__ Wq, const float* __restrict__ Wk,
    const float* __restrict__ Wv,
    unsigned short* __restrict__ MtH, unsigned short* __restrict__ MtL,
    unsigned short* __restrict__ WvT)
{
  const int idx = blockIdx.x * 256 + threadIdx.x;   // [0,4096): idx = dp*64 + d
  const int dp = idx >> 6, d = idx & 63;
  const float* wq = Wq + d * 64;
  const float* wk = Wk + dp * 64;
  float acc = 0.f;
  #pragma unroll
  for (int h = 0; h < 64; ++h) acc = fmaf(wq[h], wk[h], acc);
  acc *= LOG2E_8;
  const unsigned short hi = f2bf(acc);
  MtH[idx] = hi;
  MtL[idx] = f2bf(acc - bf2f(hi));
  WvT[idx] = f2bf(Wv[d * 64 + dp]);   // WvT[h=dp][d]
}

struct Batch {
  short8 xh[2][2], xl[2][2];
  f32x4  pa[2][2];
  char*  wl;
  float* ob;
};

__device__ __forceinline__ void load_x(const float* __restrict__ xb,
                                       f32x4 (&xr)[2][2][2], int c, int g) {
  #pragma unroll
  for (int mt = 0; mt < 2; ++mt)
    #pragma unroll
    for (int kt = 0; kt < 2; ++kt) {
      const float* p = xb + (16 * mt + c) * ND + 32 * kt + 8 * g;
      xr[mt][kt][0] = *(const f32x4*)(p);
      xr[mt][kt][1] = *(const f32x4*)(p + 4);
    }
}

// hi/lo split of 8 consecutive floats into packed bf16 words (Markidis)
__device__ __forceinline__ void split8(const f32x4 a0, const f32x4 a1,
                                       short8& hi, short8& lo) {
  u32x4 hw, lw;
  #pragma unroll
  for (int w = 0; w < 2; ++w) {
    {
      const float x0 = a0[2 * w], x1 = a0[2 * w + 1];
      const unsigned int h = pkrn(x0, x1);
      const float2 hf = unpk(h);
      hw[w] = h;
      lw[w] = pkrn(x0 - hf.x, x1 - hf.y);
    }
    {
      const float x0 = a1[2 * w], x1 = a1[2 * w + 1];
      const unsigned int h = pkrn(x0, x1);
      const float2 hf = unpk(h);
      hw[2 + w] = h;
      lw[2 + w] = pkrn(x0 - hf.x, x1 - hf.y);
    }
  }
  hi = __builtin_bit_cast(short8, hw);
  lo = __builtin_bit_cast(short8, lw);
}

__device__ __forceinline__ void split_x(Batch& s, const f32x4 (&xr)[2][2][2]) {
  #pragma unroll
  for (int mt = 0; mt < 2; ++mt)
    #pragma unroll
    for (int kt = 0; kt < 2; ++kt)
      split8(xr[mt][kt][0], xr[mt][kt][1], s.xh[mt][kt], s.xl[mt][kt]);
  #pragma unroll
  for (int i = 0; i < 2; ++i)
    #pragma unroll
    for (int j = 0; j < 2; ++j) s.pa[i][j] = f32x4{0.f, 0.f, 0.f, 0.f};
}

// tmp = X·Mt (3-term) for one 16-col block nt = 2*kt+ntl; store hi/lo to rt
__device__ __forceinline__ void qk_fill(Batch& s, const char* lds,
                                        int kt, int ntl, int c, int g) {
  const int nt = 2 * kt + ntl;
  f32x4 a0 = {0.f, 0.f, 0.f, 0.f};
  f32x4 a1 = {0.f, 0.f, 0.f, 0.f};
  #pragma unroll
  for (int kk = 0; kk < 2; ++kk) {
    const int row = 16 * nt + c;
    const int byte = row * 128 + ((64 * kk + 16 * g) ^ ((row & 7) << 4));
    const short8 bh = *(const short8*)(lds + OFF_MH + byte);
    const short8 bl = *(const short8*)(lds + OFF_ML + byte);
    a0 = MFMA(s.xh[0][kk], bh, a0);
    a0 = MFMA(s.xh[0][kk], bl, a0);
    a0 = MFMA(s.xl[0][kk], bh, a0);
    a1 = MFMA(s.xh[1][kk], bh, a1);
    a1 = MFMA(s.xh[1][kk], bl, a1);
    a1 = MFMA(s.xl[1][kk], bh, a1);
  }
  // D-frag: tmp[row=4g+j (+16)][col=16nt+c]. Pair rows (j,j+1), hi/lo.
  const int col2 = 2 * (16 * ntl + c);
  #pragma unroll
  for (int pr = 0; pr < 2; ++pr) {
    {
      const unsigned int h = pkrn(a0[2 * pr], a0[2 * pr + 1]);
      const float2 hf = unpk(h);
      const unsigned int l = pkrn(a0[2 * pr] - hf.x, a0[2 * pr + 1] - hf.y);
      const int rb = (4 * g + 2 * pr) * PWSTR + col2;
      *(unsigned short*)(s.wl + PW_RTH + rb)         = (unsigned short)h;
      *(unsigned short*)(s.wl + PW_RTH + rb + PWSTR) = (unsigned short)(h >> 16);
      *(unsigned short*)(s.wl + PW_RTL + rb)         = (unsigned short)l;
      *(unsigned short*)(s.wl + PW_RTL + rb + PWSTR) = (unsigned short)(l >> 16);
    }
    {
      const unsigned int h = pkrn(a1[2 * pr], a1[2 * pr + 1]);
      const float2 hf = unpk(h);
      const unsigned int l = pkrn(a1[2 * pr] - hf.x, a1[2 * pr + 1] - hf.y);
      const int rb = (16 + 4 * g + 2 * pr) * PWSTR + col2;
      *(unsigned short*)(s.wl + PW_RTH + rb)         = (unsigned short)h;
      *(unsigned short*)(s.wl + PW_RTH + rb + PWSTR) = (unsigned short)(h >> 16);
      *(unsigned short*)(s.wl + PW_RTL + rb)         = (unsigned short)l;
      *(unsigned short*)(s.wl + PW_RTL + rb + PWSTR) = (unsigned short)(l >> 16);
    }
  }
}

// P^T += X·tmp^T over d' block kt (reads rt back as B-frags)
__device__ __forceinline__ void qk_consume(Batch& s, int kt, int c, int g) {
  short8 tH[2], tL[2];
  #pragma unroll
  for (int i = 0; i < 2; ++i) {
    const int off = (16 * i + c) * PWSTR + 16 * g;
    tH[i] = *(const short8*)(s.wl + PW_RTH + off);
    tL[i] = *(const short8*)(s.wl + PW_RTL + off);
  }
  #pragma unroll
  for (int mt = 0; mt < 2; ++mt)
    #pragma unroll
    for (int nt2 = 0; nt2 < 2; ++nt2) {
      s.pa[mt][nt2] = MFMA(s.xh[mt][kt], tH[nt2], s.pa[mt][nt2]);
      s.pa[mt][nt2] = MFMA(s.xl[mt][kt], tH[nt2], s.pa[mt][nt2]);
      s.pa[mt][nt2] = MFMA(s.xh[mt][kt], tL[nt2], s.pa[mt][nt2]);
    }
}

// causal mask + softmax; pa[mt][nt][j] = P[t=16nt+c][s=16mt+4g+j]; store P bf16
__device__ __forceinline__ void softmax_store(Batch& s, int c, int g) {
  char* const pbuf = s.wl + PW_P;
  #pragma unroll
  for (int nt = 0; nt < 2; ++nt) {
    const int t = 16 * nt + c;
    float v[8];
    #pragma unroll
    for (int mt = 0; mt < 2; ++mt)
      #pragma unroll
      for (int j = 0; j < 4; ++j) {
        const int sidx = 16 * mt + 4 * g + j;
        v[4 * mt + j] = (sidx <= t) ? s.pa[mt][nt][j] : -__builtin_inff();
      }
    float m = fmaxf(fmaxf(fmaxf(v[0], v[1]), fmaxf(v[2], v[3])),
                    fmaxf(fmaxf(v[4], v[5]), fmaxf(v[6], v[7])));
    m = fmaxf(m, __shfl_xor(m, 16));
    m = fmaxf(m, __shfl_xor(m, 32));
    float e[8], ssum = 0.f;
    #pragma unroll
    for (int i = 0; i < 8; ++i) { e[i] = exp2f(v[i] - m); ssum += e[i]; }
    ssum += __shfl_xor(ssum, 16);
    ssum += __shfl_xor(ssum, 32);
    const float r = __builtin_amdgcn_rcpf(ssum);
    #pragma unroll
    for (int mt = 0; mt < 2; ++mt) {
      const u32x2 w2 = {pkrn(e[4 * mt] * r, e[4 * mt + 1] * r),
                        pkrn(e[4 * mt + 2] * r, e[4 * mt + 3] * r)};
      *(u32x2*)(pbuf + t * PWSTR + 32 * mt + 8 * g) = w2;   // P[t][16mt+4g..+3]
    }
  }
}

// v = X·Wv (weights in regs), stored transposed vT[h][s] stride 80 (aliases rt)
__device__ __forceinline__ void vproj(Batch& s, const short8 (&bvr)[4][2],
                                      int c, int g) {
  #pragma unroll
  for (int nt = 0; nt < 4; ++nt) {
    f32x4 a0 = {0.f, 0.f, 0.f, 0.f};
    f32x4 a1 = {0.f, 0.f, 0.f, 0.f};
    #pragma unroll
    for (int kk = 0; kk < 2; ++kk) {
      a0 = MFMA(s.xh[0][kk], bvr[nt][kk], a0);
      a1 = MFMA(s.xh[1][kk], bvr[nt][kk], a1);
    }
    // a0[j] = V[s=4g+j][h=16nt+c]; a1[j] = V[16+4g+j][h]. Pack along s.
    char* const vrow = s.wl + PW_VT + (16 * nt + c) * PWSTR;
    const u32x2 w0 = {pkrn(a0[0], a0[1]), pkrn(a0[2], a0[3])};
    const u32x2 w1 = {pkrn(a1[0], a1[1]), pkrn(a1[2], a1[3])};
    *(u32x2*)(vrow + 8 * g)      = w0;
    *(u32x2*)(vrow + 32 + 8 * g) = w1;
  }
}

// O^T = V^T·P^T (K=32): A = vT A-frag, B = P A-layout read; store fp32 dwordx4
__device__ __forceinline__ void pv_store(Batch& s, int c, int g) {
  char* const pbuf = s.wl + PW_P;
  const short8 ap0 = *(const short8*)(pbuf + c * PWSTR + 16 * g);          // t = c
  const short8 ap1 = *(const short8*)(pbuf + (16 + c) * PWSTR + 16 * g);   // t = 16+c
  #pragma unroll
  for (int mh = 0; mh < 4; ++mh) {
    const short8 bv = *(const short8*)(s.wl + PW_VT + (16 * mh + c) * PWSTR + 16 * g);
    f32x4 o0 = {0.f, 0.f, 0.f, 0.f};
    f32x4 o1 = {0.f, 0.f, 0.f, 0.f};
    o0 = MFMA(bv, ap0, o0);   // D[m=h][n=t] = O^T
    o1 = MFMA(bv, ap1, o1);
    *(f32x4*)(s.ob + c * NH + 16 * mh + 4 * g)        = o0;
    *(f32x4*)(s.ob + (16 + c) * NH + 16 * mh + 4 * g) = o1;
  }
}

__global__ __launch_bounds__(256, 3) void head_fused(
    const float* __restrict__ x,
    const unsigned short* __restrict__ MtH, const unsigned short* __restrict__ MtL,
    const unsigned short* __restrict__ WvT,
    float* __restrict__ out, int wstride)
{
  __shared__ __align__(16) char lds[LDS_BYTES];
  const int tid = threadIdx.x;

  // ---- stage Mt hi/lo (u32 swizzled copies from ws) ----
  {
    const unsigned int* srcH = (const unsigned int*)MtH;
    const unsigned int* srcL = (const unsigned int*)MtL;
    #pragma unroll
    for (int i = 0; i < 8; ++i) {
      const int e = tid + 256 * i;            // u32 index [0,2048)
      const int row = e >> 5;
      const int byte = row * 128 + (((e & 31) * 4) ^ ((row & 7) << 4));
      *(unsigned int*)(lds + OFF_MH + byte) = srcH[e];
      *(unsigned int*)(lds + OFF_ML + byte) = srcL[e];
    }
  }
  __syncthreads();

  const int wid  = tid >> 6;
  const int lane = tid & 63;
  const int c = lane & 15;
  const int g = lane >> 4;

  // ---- WvT B-frags -> registers once per wave (wave-invariant, 32 VGPR) ----
  short8 bvr[4][2];
  #pragma unroll
  for (int nt = 0; nt < 4; ++nt)
    #pragma unroll
    for (int kk = 0; kk < 2; ++kk)
      bvr[nt][kk] = *(const short8*)(WvT + (16 * nt + c) * 64 + 32 * kk + 8 * g);

  Batch S;
  S.wl = lds + OFF_WAVE + wid * WAVE_BYTES;

  const int w = blockIdx.x * 4 + wid;         // [0, wstride)

  f32x4 xc[2][2][2], xn[2][2][2];
  load_x(x + (long)w * (CTX * ND), xc, c, g);

  #pragma unroll
  for (int it = 0; it < NB_PER_WAVE; ++it) {
    const long b = (long)w + (long)it * wstride;
    if (it + 1 < NB_PER_WAVE)
      load_x(x + (b + wstride) * (CTX * ND), xn, c, g);   // prefetch, overlaps compute
    S.ob = out + b * (CTX * NH);
    split_x(S, xc);
    #pragma unroll
    for (int kt = 0; kt < 2; ++kt) {
      qk_fill(S, lds, kt, 0, c, g);
      qk_fill(S, lds, kt, 1, c, g);
      qk_consume(S, kt, c, g);
    }
    softmax_store(S, c, g);
    vproj(S, bvr, c, g);
    pv_store(S, c, g);
    if (it + 1 < NB_PER_WAVE) {
      #pragma unroll
      for (int i = 0; i < 2; ++i)
        #pragma unroll
        for (int k = 0; k < 2; ++k)
          #pragma unroll
          for (int h = 0; h < 2; ++h) xc[i][k][h] = xn[i][k][h];
    }
  }
}

extern "C" void kernel_launch(void* const* d_in, const int* in_sizes, int n_in,
                              void* d_out, int out_size, void* d_ws, size_t ws_size,
                              hipStream_t stream) {
  // setup_inputs order: x, Wk, Wq, Wv  (all fp32)
  const float* x  = (const float*)d_in[0];
  const float* Wk = (const float*)d_in[1];
  const float* Wq = (const float*)d_in[2];
  const float* Wv = (const float*)d_in[3];
  float* out = (float*)d_out;

  unsigned short* MtH = (unsigned short*)d_ws;          // [64][64] bf16
  unsigned short* MtL = MtH + 64 * 64;
  unsigned short* WvT = MtL + 64 * 64;

  mk_m<<<dim3(16), dim3(256), 0, stream>>>(Wq, Wk, Wv, MtH, MtL, WvT);

  const int batch = in_sizes[0] / (CTX * ND);           // 16384
  const int wstride = batch / NB_PER_WAVE;              // 8192 waves
  head_fused<<<dim3(wstride / 4), dim3(256), 0, stream>>>(x, MtH, MtL, WvT, out, wstride);
}